// Round 3
// baseline (254.015 us; speedup 1.0000x reference)
//
#include <hip/hip_runtime.h>
#include <math.h>

#define F_IN 10000
#define NROWS 4096
#define CGROUPS 8
#define CH_PER_CG 5          // 40 chunks of 256 cols / 8 column-groups
#define BLK 512              // 8 waves per block
#define RPW 4                // rows per wave per pass
#define PASSES 2             // 8 waves * 4 rows * 2 passes = 64 rows per block
#define ROWBLOCKS 64         // 64 row-blocks * 64 rows = 4096 rows

typedef float v4f __attribute__((ext_vector_type(4)));

__device__ __forceinline__ v4f ntload4(const float* p) {
    return __builtin_nontemporal_load((const v4f*)p);   // keep streamed x out of L2
}

// d_ws layout: 9 float arrays of F_IN each, column-ordered:
//   [0..2]*F_IN : A_m = 1/(std*sqrt(2))
//   [3..5]*F_IN : B_m = -mean/(std*sqrt(2))
//   [6..8]*F_IN : C_m = logw_m - log(std) - 0.5*log(2*pi)
__global__ void spn_prep_kernel(const float* __restrict__ means,
                                const float* __restrict__ stds,
                                const float* __restrict__ w1,
                                const int* __restrict__ rand_idxs,
                                float* __restrict__ ws,
                                float* __restrict__ out) {
    int f = blockIdx.x * blockDim.x + threadIdx.x;
    if (f < NROWS) out[f] = 0.0f;           // zero output for atomic accumulation
    if (f >= F_IN) return;

    int j = rand_idxs[f];                   // column of x this feature reads

    float wa = w1[f * 3 + 0];
    float wb = w1[f * 3 + 1];
    float wc = w1[f * 3 + 2];
    float wm = fmaxf(fmaxf(wa, wb), wc);
    float lse = wm + __logf(__expf(wa - wm) + __expf(wb - wm) + __expf(wc - wm));

    const float INV_SQRT2 = 0.70710678118654752440f;
    const float HALF_LOG_2PI = 0.91893853320467274178f;

#pragma unroll
    for (int m = 0; m < 3; m++) {
        float w  = w1[f * 3 + m] - lse;     // log_softmax
        float sd = stds[f * 3 + m];
        float mu = means[f * 3 + m];
        float a  = INV_SQRT2 / sd;
        float b  = -mu * a;
        float c  = w - __logf(sd) - HALF_LOG_2PI;
        ws[(0 + m) * F_IN + j] = a;
        ws[(3 + m) * F_IN + j] = b;
        ws[(6 + m) * F_IN + j] = c;
    }
}

// per-column mixture term: max of 3 logprobs and s = sum exp(v - max), s in [1,3]
__device__ __forceinline__ void col_term(float xv,
                                         float a0, float b0, float c0,
                                         float a1, float b1, float c1,
                                         float a2, float b2, float c2,
                                         float& mx_out, float& s_out) {
    float u0 = fmaf(xv, a0, b0);
    float u1 = fmaf(xv, a1, b1);
    float u2 = fmaf(xv, a2, b2);
    float v0 = fmaf(-u0, u0, c0);
    float v1 = fmaf(-u1, u1, c1);
    float v2 = fmaf(-u2, u2, c2);
    float mx = fmaxf(fmaxf(v0, v1), v2);
    float me = __builtin_amdgcn_fmed3f(v0, v1, v2);
    float mn = fminf(fminf(v0, v1), v2);
    float s  = 1.0f + __expf(me - mx) + __expf(mn - mx);
    mx_out = mx;
    s_out  = s;
}

__global__ __launch_bounds__(BLK) void spn_main_kernel(const float* __restrict__ x,
                                                       const float* __restrict__ ws,
                                                       float* __restrict__ out) {
    // params for this column-group, all 5 chunks: [chunk][arr 0..8][256 floats] = 45 KB
    __shared__ v4f ldsbuf[CH_PER_CG * 9 * 64];

    const int tid  = threadIdx.x;
    const int wave = tid >> 6;
    const int lane = tid & 63;
    const int rb   = blockIdx.x >> 3;       // 0..63
    const int cg   = blockIdx.x & 7;        // 0..7

    // ---- stage params global -> LDS (once per block; 23 MB total grid-wide) ----
    const v4f* wsv = (const v4f*)ws;
    for (int i = tid; i < CH_PER_CG * 9 * 64; i += BLK) {
        int it  = i / (9 * 64);
        int rem = i - it * (9 * 64);
        int a   = rem >> 6;
        int v   = rem & 63;
        int col = (cg + it * 8) * 256 + v * 4;
        v4f val = (v4f)(0.0f);
        if (col < F_IN) val = wsv[a * (F_IN / 4) + (col >> 2)];
        ldsbuf[i] = val;
    }
    __syncthreads();

    for (int g = 0; g < PASSES; ++g) {
        const int row0 = rb * 64 + g * 32 + wave * RPW;
        const float* xr0 = x + (size_t)row0 * F_IN;

        float accm[RPW], prod[RPW];
#pragma unroll
        for (int r = 0; r < RPW; r++) { accm[r] = 0.0f; prod[r] = 1.0f; }

        // prologue: first chunk of this cg is always fully valid (col <= 2047)
        v4f xv[RPW];
        {
            int jc = cg * 256 + lane * 4;
#pragma unroll
            for (int r = 0; r < RPW; r++)
                xv[r] = ntload4(xr0 + (size_t)r * F_IN + jc);
        }

#pragma unroll
        for (int it = 0; it < CH_PER_CG; ++it) {
            const int c = cg + it * 8;
            const int jcur = c * 256 + lane * 4;
            const bool vcur = (jcur < F_IN);    // only chunk 39's high lanes invalid

            // software-pipeline next chunk's x loads (HBM) before compute
            v4f xn[RPW];
            if (it < CH_PER_CG - 1) {
                int jn = (c + 8) * 256 + lane * 4;
                int jnc = (jn < F_IN) ? jn : 0;
#pragma unroll
                for (int r = 0; r < RPW; r++)
                    xn[r] = ntload4(xr0 + (size_t)r * F_IN + jnc);
            }

            // params from LDS (conflict-free: consecutive lanes, consecutive b128)
            const v4f* Lp = ldsbuf + it * (9 * 64);
            const v4f A0 = Lp[0 * 64 + lane];
            const v4f A1 = Lp[1 * 64 + lane];
            const v4f A2 = Lp[2 * 64 + lane];
            const v4f B0 = Lp[3 * 64 + lane];
            const v4f B1 = Lp[4 * 64 + lane];
            const v4f B2 = Lp[5 * 64 + lane];
            const v4f C0 = Lp[6 * 64 + lane];
            const v4f C1 = Lp[7 * 64 + lane];
            const v4f C2 = Lp[8 * 64 + lane];

#pragma unroll
            for (int r = 0; r < RPW; r++) {
                float m0, s0, m1, s1, m2, s2, m3, s3;
                col_term(xv[r].x, A0.x, B0.x, C0.x, A1.x, B1.x, C1.x, A2.x, B2.x, C2.x, m0, s0);
                col_term(xv[r].y, A0.y, B0.y, C0.y, A1.y, B1.y, C1.y, A2.y, B2.y, C2.y, m1, s1);
                col_term(xv[r].z, A0.z, B0.z, C0.z, A1.z, B1.z, C1.z, A2.z, B2.z, C2.z, m2, s2);
                col_term(xv[r].w, A0.w, B0.w, C0.w, A1.w, B1.w, C1.w, A2.w, B2.w, C2.w, m3, s3);

                float smx = (m0 + m1) + (m2 + m3);
                float sp  = (s0 * s1) * (s2 * s3);
                accm[r] += vcur ? smx : 0.0f;
                prod[r] *= vcur ? sp : 1.0f;
            }

            if (it < CH_PER_CG - 1) {
#pragma unroll
                for (int r = 0; r < RPW; r++) xv[r] = xn[r];
            }
        }

#pragma unroll
        for (int r = 0; r < RPW; r++) {
            float part = accm[r] + __logf(prod[r]);   // prod <= 3^20, no overflow
#pragma unroll
            for (int off = 32; off > 0; off >>= 1)
                part += __shfl_xor(part, off, 64);
            if (lane == 0)
                atomicAdd(&out[row0 + r], part);
        }
    }
}

extern "C" void kernel_launch(void* const* d_in, const int* in_sizes, int n_in,
                              void* d_out, int out_size, void* d_ws, size_t ws_size,
                              hipStream_t stream) {
    const float* x         = (const float*)d_in[0];
    const float* means     = (const float*)d_in[1];
    const float* stds      = (const float*)d_in[2];
    const float* w1        = (const float*)d_in[3];
    // w2..w5 (d_in[4..7]) are identity under log_softmax over a size-1 axis
    const int*   rand_idxs = (const int*)d_in[8];

    float* out = (float*)d_out;
    float* ws  = (float*)d_ws;   // uses 9 * 10000 * 4 B = 360 KB

    // prep: column-ordered constants + zero the output
    spn_prep_kernel<<<(F_IN + 255) / 256, 256, 0, stream>>>(means, stds, w1, rand_idxs, ws, out);

    // main: 64 row-blocks (64 rows) x 8 column-groups = 512 blocks, all co-resident
    spn_main_kernel<<<ROWBLOCKS * CGROUPS, BLK, 0, stream>>>(x, ws, out);
}